// Round 5
// baseline (55.646 us; speedup 1.0000x reference)
//
#include <hip/hip_runtime.h>
#include <hip/hip_fp16.h>

#define N_CLASS_C 6

typedef int vint4 __attribute__((ext_vector_type(4)));

// 8-byte packed atom record: fp16 x,y,z,radius. One dwordx2 gather per atom.
struct alignas(8) HAtom {
    __half x, y, z, r;
};

__global__ void zero_accum(float* accum) {
    if (threadIdx.x < N_CLASS_C) accum[threadIdx.x] = 0.0f;
}

__global__ void prep_atoms(const float* __restrict__ coords,
                           const float* __restrict__ radii,
                           const int* __restrict__ names,
                           HAtom* __restrict__ atoms,
                           int n_atoms) {
    int i = blockIdx.x * blockDim.x + threadIdx.x;
    if (i < n_atoms) {
        HAtom a;
        a.x = __float2half(coords[3 * i + 0]);
        a.y = __float2half(coords[3 * i + 1]);
        a.z = __float2half(coords[3 * i + 2]);
        a.r = __float2half(radii[names[i]]);
        atoms[i] = a;
    }
}

__device__ __forceinline__ void block_reduce_accum(float* s, float* accum) {
    __shared__ float sh[N_CLASS_C];
    if (threadIdx.x < N_CLASS_C) sh[threadIdx.x] = 0.0f;
    __syncthreads();
#pragma unroll
    for (int c = 0; c < N_CLASS_C; ++c) {
        float v = s[c];
#pragma unroll
        for (int off = 32; off > 0; off >>= 1) v += __shfl_down(v, off, 64);
        if ((threadIdx.x & 63) == 0 && v != 0.0f) atomicAdd(&sh[c], v);
    }
    __syncthreads();
    if (threadIdx.x < N_CLASS_C) {
        float v = sh[threadIdx.x];
        if (v != 0.0f) atomicAdd(&accum[threadIdx.x], v);
    }
}

__device__ __forceinline__ float hdist_base(const HAtom& A, const HAtom& B) {
    float dx = __half2float(A.x) - __half2float(B.x);
    float dy = __half2float(A.y) - __half2float(B.y);
    float dz = __half2float(A.z) - __half2float(B.z);
    float dist = sqrtf(dx * dx + dy * dy + dz * dz + 1e-12f);
    return (__half2float(A.r) + __half2float(B.r)) - dist;
}

#define K_GRP 2

// Each thread owns K_GRP groups (8 pairs). ALL loads (2*K pair int4s, then
// 8*K atom gathers) are issued before any compute: sched_barrier(0) pins the
// boundary so the compiler cannot interleave compute and shrink MLP.
__global__ __launch_bounds__(256) void clash_main(
    const int* __restrict__ pairs,      // 2 * n_pairs
    const HAtom* __restrict__ atoms,
    const int* __restrict__ masks,      // N_CLASS * n_pairs
    const float* __restrict__ tol,
    float* __restrict__ accum,
    int n_pairs, int T, int ngroups) {
    float tc[N_CLASS_C];
#pragma unroll
    for (int c = 0; c < N_CLASS_C; ++c) tc[c] = tol[c];
    float tmax = tc[0];
#pragma unroll
    for (int c = 1; c < N_CLASS_C; ++c) tmax = fmaxf(tmax, tc[c]);

    float s[N_CLASS_C];
#pragma unroll
    for (int c = 0; c < N_CLASS_C; ++c) s[c] = 0.0f;

    const int tid = blockIdx.x * blockDim.x + threadIdx.x;
    const vint4* pairs4 = reinterpret_cast<const vint4*>(pairs);

    if (tid < T) {
        // ---- issue all pair loads ----
        vint4 pa[K_GRP], pb[K_GRP];
#pragma unroll
        for (int k = 0; k < K_GRP; ++k) {
            int g = tid + k * T;
            pa[k] = pairs4[2 * g];
            pb[k] = pairs4[2 * g + 1];
        }
        __builtin_amdgcn_sched_barrier(0);
        // ---- issue all atom gathers ----
        HAtom A[K_GRP][4], B[K_GRP][4];
#pragma unroll
        for (int k = 0; k < K_GRP; ++k) {
            int i0[4] = {pa[k].x, pa[k].z, pb[k].x, pb[k].z};
            int i1[4] = {pa[k].y, pa[k].w, pb[k].y, pb[k].w};
#pragma unroll
            for (int j = 0; j < 4; ++j) {
                A[k][j] = atoms[i0[j]];
                B[k][j] = atoms[i1[j]];
            }
        }
        __builtin_amdgcn_sched_barrier(0);
        // ---- compute ----
#pragma unroll
        for (int k = 0; k < K_GRP; ++k) {
            float base[4];
#pragma unroll
            for (int j = 0; j < 4; ++j) base[j] = hdist_base(A[k][j], B[k][j]);
            float bm = fmaxf(fmaxf(base[0], base[1]), fmaxf(base[2], base[3]));
            if (bm + tmax > 0.0f) {   // per-lane branch: ~2% of lanes
                int g = tid + k * T;
#pragma unroll
                for (int c = 0; c < N_CLASS_C; ++c) {
                    const int* mrow = masks + (size_t)c * n_pairs + 4 * (size_t)g;
                    float acc = 0.0f;
                    if (mrow[0]) acc += fmaxf(base[0] + tc[c], 0.0f);
                    if (mrow[1]) acc += fmaxf(base[1] + tc[c], 0.0f);
                    if (mrow[2]) acc += fmaxf(base[2] + tc[c], 0.0f);
                    if (mrow[3]) acc += fmaxf(base[3] + tc[c], 0.0f);
                    s[c] += acc;
                }
            }
        }
    }

    // Leftover groups [K*T, ngroups)
    {
        int g = K_GRP * T + tid;
        if (g < ngroups) {
            vint4 pa = pairs4[2 * g];
            vint4 pb = pairs4[2 * g + 1];
            int i0[4] = {pa.x, pa.z, pb.x, pb.z};
            int i1[4] = {pa.y, pa.w, pb.y, pb.w};
            float base[4];
#pragma unroll
            for (int j = 0; j < 4; ++j) base[j] = hdist_base(atoms[i0[j]], atoms[i1[j]]);
            float bm = fmaxf(fmaxf(base[0], base[1]), fmaxf(base[2], base[3]));
            if (bm + tmax > 0.0f) {
#pragma unroll
                for (int c = 0; c < N_CLASS_C; ++c) {
                    const int* mrow = masks + (size_t)c * n_pairs + 4 * (size_t)g;
                    float acc = 0.0f;
                    if (mrow[0]) acc += fmaxf(base[0] + tc[c], 0.0f);
                    if (mrow[1]) acc += fmaxf(base[1] + tc[c], 0.0f);
                    if (mrow[2]) acc += fmaxf(base[2] + tc[c], 0.0f);
                    if (mrow[3]) acc += fmaxf(base[3] + tc[c], 0.0f);
                    s[c] += acc;
                }
            }
        }
    }

    // Leftover pairs [4*ngroups, n_pairs)
    {
        int p = 4 * ngroups + tid;
        if (p < n_pairs) {
            int a0 = pairs[2 * p], a1 = pairs[2 * p + 1];
            float base = hdist_base(atoms[a0], atoms[a1]);
            if (base + tmax > 0.0f) {
#pragma unroll
                for (int c = 0; c < N_CLASS_C; ++c) {
                    if (masks[(size_t)c * n_pairs + p])
                        s[c] += fmaxf(base + tc[c], 0.0f);
                }
            }
        }
    }

    block_reduce_accum(s, accum);
}

__global__ void finalize(const float* __restrict__ accum,
                         const float* __restrict__ w,
                         float* __restrict__ out) {
    int c = threadIdx.x;
    if (c < N_CLASS_C) {
        float scale = expf(w[0]);
        out[c] = accum[c] * scale;
    }
}

// -------- fallback (tiny ws): direct gather path, fp32, no atoms table --------
__global__ __launch_bounds__(256) void clash_fallback(
    const int* __restrict__ pairs,
    const float* __restrict__ coords,
    const float* __restrict__ radii,
    const int* __restrict__ names,
    const int* __restrict__ masks,
    const float* __restrict__ tol,
    float* __restrict__ accum,
    int n_pairs) {
    float tc[N_CLASS_C];
#pragma unroll
    for (int c = 0; c < N_CLASS_C; ++c) tc[c] = tol[c];
    float tmax = tc[0];
#pragma unroll
    for (int c = 1; c < N_CLASS_C; ++c) tmax = fmaxf(tmax, tc[c]);
    float s[N_CLASS_C];
#pragma unroll
    for (int c = 0; c < N_CLASS_C; ++c) s[c] = 0.0f;

    const int tid = blockIdx.x * blockDim.x + threadIdx.x;
    const int stride = gridDim.x * blockDim.x;
    for (int p = tid; p < n_pairs; p += stride) {
        int a0 = pairs[2 * p], a1 = pairs[2 * p + 1];
        float dx = coords[3 * a0] - coords[3 * a1];
        float dy = coords[3 * a0 + 1] - coords[3 * a1 + 1];
        float dz = coords[3 * a0 + 2] - coords[3 * a1 + 2];
        float dist = sqrtf(dx * dx + dy * dy + dz * dz + 1e-12f);
        float base = (radii[names[a0]] + radii[names[a1]]) - dist;
        if (base + tmax > 0.0f) {
#pragma unroll
            for (int c = 0; c < N_CLASS_C; ++c) {
                if (masks[(size_t)c * n_pairs + p])
                    s[c] += fmaxf(base + tc[c], 0.0f);
            }
        }
    }
    block_reduce_accum(s, accum);
}

extern "C" void kernel_launch(void* const* d_in, const int* in_sizes, int n_in,
                              void* d_out, int out_size, void* d_ws, size_t ws_size,
                              hipStream_t stream) {
    const float* coords = (const float*)d_in[0];
    const float* radii  = (const float*)d_in[1];
    const float* tol    = (const float*)d_in[2];
    const float* weight = (const float*)d_in[3];
    const int* names    = (const int*)d_in[4];
    const int* pairs    = (const int*)d_in[5];
    const int* masks    = (const int*)d_in[6];
    float* out = (float*)d_out;

    int n_atoms = in_sizes[4];
    int n_pairs = in_sizes[5] / 2;

    const size_t hdr_bytes = 256;
    size_t atoms_bytes = (size_t)n_atoms * sizeof(HAtom);

    if (ws_size >= hdr_bytes + atoms_bytes) {
        float* accum = (float*)d_ws;
        HAtom* atoms = (HAtom*)((char*)d_ws + hdr_bytes);

        prep_atoms<<<(n_atoms + 255) / 256, 256, 0, stream>>>(coords, radii, names, atoms, n_atoms);
        zero_accum<<<1, 64, 0, stream>>>(accum);

        int ngroups = n_pairs >> 2;
        int T = ngroups / K_GRP;           // threads in main phase (K groups each)
        int nthreads = T > 0 ? T : 256;    // ensure tail coverage for tiny inputs
        int blocks = (nthreads + 255) / 256;
        clash_main<<<blocks, 256, 0, stream>>>(pairs, atoms, masks, tol, accum,
                                               n_pairs, T, ngroups);
        finalize<<<1, 64, 0, stream>>>(accum, weight, out);
    } else {
        float* accum = out;
        zero_accum<<<1, 64, 0, stream>>>(accum);
        clash_fallback<<<2048, 256, 0, stream>>>(pairs, coords, radii, names,
                                                 masks, tol, accum, n_pairs);
        finalize<<<1, 64, 0, stream>>>(accum, weight, out);
    }
}